// Round 7
// baseline (896.738 us; speedup 1.0000x reference)
//
#include <hip/hip_runtime.h>
#include <math.h>

#define DIMM 768
#define SEQ 2048
#define BATB 2
#define NHEAD 12
#define DHEAD 64
#define ROWS 4096

typedef __attribute__((ext_vector_type(8))) short bf16x8;
typedef __attribute__((ext_vector_type(4))) float f32x4;
typedef unsigned short ushort_t;
typedef unsigned int uint_t;

union U16 { int4 i; ushort_t u[8]; };

__device__ __forceinline__ ushort_t f2b(float f) {
    uint_t u = __float_as_uint(f);
    return (ushort_t)((u + 0x7FFFu + ((u >> 16) & 1u)) >> 16);
}

// ---------------------------------------------------------------- weight transpose fp32[k][n] -> bf16[n][k]
struct WPtrs { const float* s[6]; };
struct BPtrs { const float* p[3]; };

__global__ __launch_bounds__(256) void wtrans_k(WPtrs wp, ushort_t* __restrict__ dst)
{
    __shared__ float T[64][65];
    int wi = blockIdx.z;
    const float* in = wp.s[wi];
    ushort_t* out = dst + (size_t)wi * (DIMM * DIMM);
    int kb = blockIdx.y * 64, nb = blockIdx.x * 64;
    int t = threadIdx.x;
    int kl = t >> 4, nl = (t & 15) * 4;
    #pragma unroll
    for (int it = 0; it < 4; it++) {
        float4 a = *(const float4*)&in[(size_t)(kb + kl + it * 16) * DIMM + nb + nl];
        T[kl + it * 16][nl + 0] = a.x;
        T[kl + it * 16][nl + 1] = a.y;
        T[kl + it * 16][nl + 2] = a.z;
        T[kl + it * 16][nl + 3] = a.w;
    }
    __syncthreads();
    int no = t >> 2, ko = (t & 3) * 16;
    #pragma unroll
    for (int j = 0; j < 2; j++) {
        U16 u;
        #pragma unroll
        for (int c = 0; c < 8; c++) u.u[c] = f2b(T[ko + j * 8 + c][no]);
        *(int4*)&out[(size_t)(nb + no) * DIMM + kb + ko + j * 8] = u.i;
    }
}

// ---------------------------------------------------------------- LayerNorm (fp32 in -> bf16 out)
__global__ __launch_bounds__(256) void ln_k(const float* __restrict__ x,
                                            const float* __restrict__ w,
                                            const float* __restrict__ b,
                                            ushort_t* __restrict__ out)
{
    int row = blockIdx.x;
    int tid = threadIdx.x;
    const float* xr = x + (size_t)row * DIMM;
    float v0 = xr[tid], v1 = xr[tid + 256], v2 = xr[tid + 512];
    float s  = v0 + v1 + v2;
    float ss = v0 * v0 + v1 * v1 + v2 * v2;
    #pragma unroll
    for (int off = 32; off > 0; off >>= 1) {
        s  += __shfl_down(s,  off);
        ss += __shfl_down(ss, off);
    }
    __shared__ float ws_[4], wss_[4];
    __shared__ float mu_s, rs_s;
    int lane = tid & 63, wid = tid >> 6;
    if (lane == 0) { ws_[wid] = s; wss_[wid] = ss; }
    __syncthreads();
    if (tid == 0) {
        float S1 = ws_[0] + ws_[1] + ws_[2] + ws_[3];
        float S2 = wss_[0] + wss_[1] + wss_[2] + wss_[3];
        float m = S1 * (1.0f / DIMM);
        float var = S2 * (1.0f / DIMM) - m * m;
        mu_s = m;
        rs_s = rsqrtf(var + 1e-5f);
    }
    __syncthreads();
    float mu = mu_s, rs = rs_s;
    ushort_t* orow = out + (size_t)row * DIMM;
    orow[tid]       = f2b((v0 - mu) * rs * w[tid]       + b[tid]);
    orow[tid + 256] = f2b((v1 - mu) * rs * w[tid + 256] + b[tid + 256]);
    orow[tid + 512] = f2b((v2 - mu) * rs * w[tid + 512] + b[tid + 512]);
}

// ---------------------------------------------------------------- MFMA GEMM — LDS-FREE, barrier-free
// C[4096,N] = A[4096,768] @ W[768,N] + bias
// Rationale: K=768 (12 K-steps) never amortizes LDS staging barriers; B is
// 1.2 MB (L2-resident) and A is L3-resident. Each WAVE independently computes
// a 16-row x 64-col strip, loading A/B MFMA fragments global->VGPR directly
// (lane holds [row=lane&15][k=(lane>>4)*8..+8] = natural fragment layout,
// 16B/lane). Software-pipelined one K-step ahead; zero LDS, zero barriers,
// 3072 independent waves for the QKV dispatch (12/CU).
template<int ASRC, int OMODE, bool RELU, bool RES, int NB>
__global__ __launch_bounds__(256) void mgemm_k(const ushort_t* __restrict__ A,
                                               const ushort_t* __restrict__ BT,
                                               BPtrs bias,
                                               const float* __restrict__ res,
                                               void* __restrict__ outv)
{
    int tid = threadIdx.x;
    int lane = tid & 63, w = tid >> 6;
    int col_l = lane & 15, quad = lane >> 4;
    int q8 = quad * 8;
    int colBase = blockIdx.x * 64;
    int rowBase = blockIdx.y * 64;
    int arow = rowBase + w * 16 + col_l;          // A-fragment row for this lane

    // A fragment base (k added per step)
    size_t abase;
    if (ASRC == 1) abase = (size_t)arow * DIMM;
    else           abase = ((size_t)(arow >> 11) * SEQ + (arow & 2047)) * DHEAD;
    const size_t HSTR = (size_t)BATB * SEQ * DHEAD;   // per-head stride (ASRC==2)

    // B fragment bases for the 4 n-tiles (BT row-major [n][k])
    size_t bbase[4];
    #pragma unroll
    for (int nt = 0; nt < 4; nt++)
        bbase[nt] = (size_t)(colBase + nt * 16 + col_l) * DIMM;

    f32x4 acc[4];
    #pragma unroll
    for (int nt = 0; nt < 4; nt++) { f32x4 z = {0.f, 0.f, 0.f, 0.f}; acc[nt] = z; }

    // fragment loaders
    auto lda = [&](int kt) -> bf16x8 {
        size_t off;
        if (ASRC == 1) off = abase + kt + q8;
        else           off = abase + (size_t)(kt >> 6) * HSTR + (kt & 63) + q8;
        // note: kt%32==0 and q8<32 => (kt&63)+q8 < 64, head index = kt>>6 exactly
        return *(const bf16x8*)&A[off];
    };

    bf16x8 aC = lda(0);
    bf16x8 bC[4];
    #pragma unroll
    for (int nt = 0; nt < 4; nt++) bC[nt] = *(const bf16x8*)&BT[bbase[nt] + q8];

    #pragma unroll
    for (int kt = 0; kt < DIMM - 32; kt += 32) {
        bf16x8 aN = lda(kt + 32);
        bf16x8 bN[4];
        #pragma unroll
        for (int nt = 0; nt < 4; nt++) bN[nt] = *(const bf16x8*)&BT[bbase[nt] + kt + 32 + q8];
        #pragma unroll
        for (int nt = 0; nt < 4; nt++)
            acc[nt] = __builtin_amdgcn_mfma_f32_16x16x32_bf16(aC, bC[nt], acc[nt], 0, 0, 0);
        aC = aN;
        #pragma unroll
        for (int nt = 0; nt < 4; nt++) bC[nt] = bN[nt];
    }
    #pragma unroll
    for (int nt = 0; nt < 4; nt++)
        acc[nt] = __builtin_amdgcn_mfma_f32_16x16x32_bf16(aC, bC[nt], acc[nt], 0, 0, 0);

    // ---- epilogue (C layout: col = lane&15 within 16-tile, row = quad*4+reg)
    int wi = (NB == 3) ? (int)(blockIdx.x / 12) : 0;
    const float* bp_ = bias.p[wi];
    int nLoc0 = colBase - wi * DIMM;
    #pragma unroll
    for (int nt = 0; nt < 4; nt++) {
        int n = colBase + nt * 16 + col_l;
        float bn = bp_[nLoc0 + nt * 16 + col_l];
        #pragma unroll
        for (int r = 0; r < 4; r++) {
            int row = rowBase + w * 16 + quad * 4 + r;
            float v = acc[nt][r] + bn;
            if (RELU) v = fmaxf(v, 0.0f);
            if (RES)  v += res[(size_t)row * DIMM + n];
            if (OMODE == 0) {
                ((float*)outv)[(size_t)row * DIMM + n] = v;
            } else if (OMODE == 1) {
                ((ushort_t*)outv)[(size_t)row * DIMM + n] = f2b(v);
            } else {
                ((ushort_t*)outv)[((size_t)((n >> 6) * BATB + (row >> 11)) * SEQ + (row & 2047)) * DHEAD + (n & 63)] = f2b(v);
            }
        }
    }
}

// ---------------------------------------------------------------- MFMA flash attention (round-0 baseline form — best measured)
// q,k,v bf16 [hb][s][64]; bias fp32 [hb][s][s]; mask int [b][s][s]; out bf16 [hb][s][64]
__global__ __launch_bounds__(256) void attn_k(const ushort_t* __restrict__ q,
                                              const ushort_t* __restrict__ k,
                                              const ushort_t* __restrict__ v,
                                              const float* __restrict__ bias,
                                              const int* __restrict__ mask,
                                              ushort_t* __restrict__ out)
{
    __shared__ alignas(16) ushort_t Kf[8 * 64 * 8];
    __shared__ alignas(16) ushort_t Vf[8 * 64 * 8];
    __shared__ alignas(16) ushort_t Pf[8 * 64 * 8];
    int tid = threadIdx.x, lane = tid & 63, w = tid >> 6;
    int col_l = lane & 15, quad = lane >> 4;
    int qbase = blockIdx.x * 64;
    int hb = blockIdx.y;
    const ushort_t* qp = q + (size_t)hb * SEQ * DHEAD;
    const ushort_t* kp = k + (size_t)hb * SEQ * DHEAD;
    const ushort_t* vp = v + (size_t)hb * SEQ * DHEAD;
    const float* bp = bias + (size_t)hb * SEQ * SEQ;
    const int*   mp = mask + (size_t)(hb & 1) * SEQ * SEQ;

    // Q A-fragments (lane holds Q[m=lane&15][(lane>>4)*8 + i]), 2 k-halves
    bf16x8 qF0 = *(const bf16x8*)&qp[(size_t)(qbase + w * 16 + col_l) * DHEAD + (quad * 8)];
    bf16x8 qF1 = *(const bf16x8*)&qp[(size_t)(qbase + w * 16 + col_l) * DHEAD + 32 + (quad * 8)];

    f32x4 O[4];
    #pragma unroll
    for (int nt = 0; nt < 4; nt++) { f32x4 z = {0.f, 0.f, 0.f, 0.f}; O[nt] = z; }
    float m_run[4], l_run[4];
    #pragma unroll
    for (int r = 0; r < 4; r++) { m_run[r] = -1e30f; l_run[r] = 0.0f; }

    int sn = tid >> 2, sko = (tid & 3) * 16;   // K staging
    int j0 = (tid >> 3) * 2, e0 = (tid & 7) * 8; // V staging (row pair)

    for (int kvb = 0; kvb < SEQ; kvb += 64) {
        // ---- stage K tile, fragment order (straight 16B copies)
        #pragma unroll
        for (int jj = 0; jj < 2; jj++) {
            int kk = sko + jj * 8;
            int4 kd = *(const int4*)&kp[(size_t)(kvb + sn) * DHEAD + kk];
            int slot = (kk >> 5) * 4 + (sn >> 4);
            int ln = (sn & 15) | (((kk & 31) >> 3) << 4);
            *(int4*)&Kf[(slot * 64 + ln) * 8] = kd;
        }
        // ---- stage V tile transposed into fragment order (paired rows -> b32 writes)
        {
            U16 g0, g1;
            g0.i = *(const int4*)&vp[(size_t)(kvb + j0) * DHEAD + e0];
            g1.i = *(const int4*)&vp[(size_t)(kvb + j0 + 1) * DHEAD + e0];
            int js = j0 >> 5, grp = (j0 & 31) >> 3, i0 = j0 & 7;
            #pragma unroll
            for (int c = 0; c < 8; c++) {
                int n = e0 + c;
                uint_t pk = (uint_t)g0.u[c] | ((uint_t)g1.u[c] << 16);
                int idx = ((js * 4 + (n >> 4)) * 64 + ((n & 15) | (grp << 4))) * 8 + i0;
                *(uint_t*)&Vf[idx] = pk;
            }
        }
        // ---- bias + mask loads (issued early; overlap staging+MFMA latency)
        float bl[4][4]; int ml[4][4];
        #pragma unroll
        for (int nt = 0; nt < 4; nt++) {
            int col = kvb + nt * 16 + col_l;
            #pragma unroll
            for (int r = 0; r < 4; r++) {
                int qrow = qbase + w * 16 + quad * 4 + r;
                bl[nt][r] = bp[(size_t)qrow * SEQ + col];
                ml[nt][r] = mp[(size_t)qrow * SEQ + col];
            }
        }
        __syncthreads();
        // ---- S = Q K^T
        f32x4 S[4];
        #pragma unroll
        for (int nt = 0; nt < 4; nt++) {
            bf16x8 b0 = *(bf16x8*)&Kf[((0 * 4 + nt) * 64 + lane) * 8];
            bf16x8 b1 = *(bf16x8*)&Kf[((1 * 4 + nt) * 64 + lane) * 8];
            f32x4 z = {0.f, 0.f, 0.f, 0.f};
            z = __builtin_amdgcn_mfma_f32_16x16x32_bf16(qF0, b0, z, 0, 0, 0);
            S[nt] = __builtin_amdgcn_mfma_f32_16x16x32_bf16(qF1, b1, z, 0, 0, 0);
        }
        // ---- logits
        float lg[4][4];
        #pragma unroll
        for (int nt = 0; nt < 4; nt++)
            #pragma unroll
            for (int r = 0; r < 4; r++)
                lg[nt][r] = ml[nt][r] ? (S[nt][r] + bl[nt][r]) * 0.125f : -1.25e19f;
        // ---- online softmax (rows live in 16-lane quads)
        float alpha[4];
        #pragma unroll
        for (int r = 0; r < 4; r++) {
            float mx = fmaxf(fmaxf(lg[0][r], lg[1][r]), fmaxf(lg[2][r], lg[3][r]));
            mx = fmaxf(mx, __shfl_xor(mx, 1));
            mx = fmaxf(mx, __shfl_xor(mx, 2));
            mx = fmaxf(mx, __shfl_xor(mx, 4));
            mx = fmaxf(mx, __shfl_xor(mx, 8));
            float mnew = fmaxf(m_run[r], mx);
            alpha[r] = __expf(m_run[r] - mnew);
            m_run[r] = mnew;
            float rs = 0.0f;
            #pragma unroll
            for (int nt = 0; nt < 4; nt++) {
                float p = __expf(lg[nt][r] - mnew);
                lg[nt][r] = p;
                rs += p;
            }
            rs += __shfl_xor(rs, 1);
            rs += __shfl_xor(rs, 2);
            rs += __shfl_xor(rs, 4);
            rs += __shfl_xor(rs, 8);
            l_run[r] = l_run[r] * alpha[r] + rs;
        }
        #pragma unroll
        for (int nt = 0; nt < 4; nt++)
            #pragma unroll
            for (int r = 0; r < 4; r++)
                O[nt][r] *= alpha[r];
        // ---- P (C-layout) -> bf16 -> Pf (A-fragment order, wave-private)
        #pragma unroll
        for (int nt = 0; nt < 4; nt++) {
            int j = nt * 16 + col_l;
            #pragma unroll
            for (int r = 0; r < 4; r++) {
                ushort_t pu = f2b(lg[nt][r]);
                uint_t po = (uint_t)(unsigned)__shfl_xor((int)pu, 1);
                if ((lane & 1) == 0) {
                    int m = quad * 4 + r;
                    int idx = ((w * 2 + (j >> 5)) * 64 + (m | (((j & 31) >> 3) << 4))) * 8 + (j & 7);
                    *(uint_t*)&Pf[idx] = (uint_t)pu | (po << 16);
                }
            }
        }
        // ---- O += P V
        #pragma unroll
        for (int js = 0; js < 2; js++) {
            bf16x8 pF = *(bf16x8*)&Pf[((w * 2 + js) * 64 + lane) * 8];
            #pragma unroll
            for (int nt = 0; nt < 4; nt++) {
                bf16x8 vF = *(bf16x8*)&Vf[((js * 4 + nt) * 64 + lane) * 8];
                O[nt] = __builtin_amdgcn_mfma_f32_16x16x32_bf16(pF, vF, O[nt], 0, 0, 0);
            }
        }
        __syncthreads();
    }
    // ---- write out bf16 [hb][s][dh]
    float inv[4];
    #pragma unroll
    for (int r = 0; r < 4; r++) inv[r] = 1.0f / l_run[r];
    #pragma unroll
    for (int nt = 0; nt < 4; nt++)
        #pragma unroll
        for (int r = 0; r < 4; r++) {
            int row = qbase + w * 16 + quad * 4 + r;
            out[((size_t)hb * SEQ + row) * DHEAD + nt * 16 + col_l] = f2b(O[nt][r] * inv[r]);
        }
}

// ---------------------------------------------------------------- launch
extern "C" void kernel_launch(void* const* d_in, const int* in_sizes, int n_in,
                              void* d_out, int out_size, void* d_ws, size_t ws_size,
                              hipStream_t stream)
{
    const float* x    = (const float*)d_in[0];
    const float* bias = (const float*)d_in[1];
    const int*   mask = (const int*)d_in[2];
    const float* ln1w = (const float*)d_in[3];
    const float* ln1b = (const float*)d_in[4];
    const float* wq   = (const float*)d_in[5];
    const float* bq   = (const float*)d_in[6];
    const float* wk   = (const float*)d_in[7];
    const float* bk   = (const float*)d_in[8];
    const float* wv   = (const float*)d_in[9];
    const float* bv   = (const float*)d_in[10];
    const float* wo   = (const float*)d_in[11];
    const float* bo   = (const float*)d_in[12];
    const float* ln2w = (const float*)d_in[13];
    const float* ln2b = (const float*)d_in[14];
    const float* w1   = (const float*)d_in[15];
    const float* b1   = (const float*)d_in[16];
    const float* w2   = (const float*)d_in[17];
    const float* b2   = (const float*)d_in[18];

    const size_t WSZ = (size_t)DIMM * DIMM;        // 589824
    const size_t ABUF = (size_t)ROWS * DIMM;       // 3145728

    ushort_t* wsu  = (ushort_t*)d_ws;
    ushort_t* wT   = wsu;                          // 6 transposed bf16 weights
    ushort_t* qb   = wsu + 6 * WSZ;
    ushort_t* kbuf = qb + ABUF;
    ushort_t* vbuf = kbuf + ABUF;
    ushort_t* xn1  = vbuf + ABUF;                  // LN1 out; reused: attnout, LN2 out
    float*    x1   = (float*)(xn1 + ABUF);         // fp32 post-attn residual
    ushort_t* hid  = qb;                           // FFN hidden reuses q

    WPtrs wp; wp.s[0] = wq; wp.s[1] = wk; wp.s[2] = wv; wp.s[3] = wo; wp.s[4] = w1; wp.s[5] = w2;
    BPtrs bqkv; bqkv.p[0] = bq; bqkv.p[1] = bk; bqkv.p[2] = bv;
    BPtrs bbo;  bbo.p[0]  = bo; bbo.p[1]  = bo; bbo.p[2]  = bo;
    BPtrs bb1;  bb1.p[0]  = b1; bb1.p[1]  = b1; bb1.p[2]  = b1;
    BPtrs bb2;  bb2.p[0]  = b2; bb2.p[1]  = b2; bb2.p[2]  = b2;

    dim3 gg(12, 64), gb(256);                      // 64-col x 64-row blocks (4 waves, 16 rows each)
    wtrans_k<<<dim3(12, 12, 6), 256, 0, stream>>>(wp, wT);
    ln_k<<<ROWS, 256, 0, stream>>>(x, ln1w, ln1b, xn1);
    // fused QKV: one GEMM, N=2304; scatter lands q->qb, k->kbuf, v->vbuf automatically
    mgemm_k<1, 2, false, false, 3><<<dim3(36, 64), gb, 0, stream>>>(xn1, wT, bqkv, nullptr, qb);
    attn_k<<<dim3(32, 24), 256, 0, stream>>>(qb, kbuf, vbuf, bias, mask, xn1);
    mgemm_k<2, 0, false, true, 1><<<gg, gb, 0, stream>>>(xn1, wT + 3 * WSZ, bbo, x, x1);
    ln_k<<<ROWS, 256, 0, stream>>>(x1, ln2w, ln2b, xn1);
    mgemm_k<1, 1, true, false, 1><<<gg, gb, 0, stream>>>(xn1, wT + 4 * WSZ, bb1, nullptr, hid);
    mgemm_k<1, 0, false, true, 1><<<gg, gb, 0, stream>>>(hid, wT + 5 * WSZ, bb2, x1, (float*)d_out);
}

// Round 8
// 760.765 us; speedup vs baseline: 1.1787x; 1.1787x over previous
//
#include <hip/hip_runtime.h>
#include <math.h>

#define DIMM 768
#define SEQ 2048
#define BATB 2
#define NHEAD 12
#define DHEAD 64
#define ROWS 4096

typedef __attribute__((ext_vector_type(8))) short bf16x8;
typedef __attribute__((ext_vector_type(4))) float f32x4;
typedef unsigned short ushort_t;
typedef unsigned int uint_t;

union U16 { int4 i; ushort_t u[8]; };

__device__ __forceinline__ ushort_t f2b(float f) {
    uint_t u = __float_as_uint(f);
    return (ushort_t)((u + 0x7FFFu + ((u >> 16) & 1u)) >> 16);
}

// ---------------------------------------------------------------- weight transpose fp32[k][n] -> bf16[n][k]
struct WPtrs { const float* s[6]; };
struct BPtrs { const float* p[3]; };

__global__ __launch_bounds__(256) void wtrans_k(WPtrs wp, ushort_t* __restrict__ dst)
{
    __shared__ float T[64][65];
    int wi = blockIdx.z;
    const float* in = wp.s[wi];
    ushort_t* out = dst + (size_t)wi * (DIMM * DIMM);
    int kb = blockIdx.y * 64, nb = blockIdx.x * 64;
    int t = threadIdx.x;
    int kl = t >> 4, nl = (t & 15) * 4;
    #pragma unroll
    for (int it = 0; it < 4; it++) {
        float4 a = *(const float4*)&in[(size_t)(kb + kl + it * 16) * DIMM + nb + nl];
        T[kl + it * 16][nl + 0] = a.x;
        T[kl + it * 16][nl + 1] = a.y;
        T[kl + it * 16][nl + 2] = a.z;
        T[kl + it * 16][nl + 3] = a.w;
    }
    __syncthreads();
    int no = t >> 2, ko = (t & 3) * 16;
    #pragma unroll
    for (int j = 0; j < 2; j++) {
        U16 u;
        #pragma unroll
        for (int c = 0; c < 8; c++) u.u[c] = f2b(T[ko + j * 8 + c][no]);
        *(int4*)&out[(size_t)(nb + no) * DIMM + kb + ko + j * 8] = u.i;
    }
}

// ---------------------------------------------------------------- LayerNorm (fp32 in -> bf16 out)
__global__ __launch_bounds__(256) void ln_k(const float* __restrict__ x,
                                            const float* __restrict__ w,
                                            const float* __restrict__ b,
                                            ushort_t* __restrict__ out)
{
    int row = blockIdx.x;
    int tid = threadIdx.x;
    const float* xr = x + (size_t)row * DIMM;
    float v0 = xr[tid], v1 = xr[tid + 256], v2 = xr[tid + 512];
    float s  = v0 + v1 + v2;
    float ss = v0 * v0 + v1 * v1 + v2 * v2;
    #pragma unroll
    for (int off = 32; off > 0; off >>= 1) {
        s  += __shfl_down(s,  off);
        ss += __shfl_down(ss, off);
    }
    __shared__ float ws_[4], wss_[4];
    __shared__ float mu_s, rs_s;
    int lane = tid & 63, wid = tid >> 6;
    if (lane == 0) { ws_[wid] = s; wss_[wid] = ss; }
    __syncthreads();
    if (tid == 0) {
        float S1 = ws_[0] + ws_[1] + ws_[2] + ws_[3];
        float S2 = wss_[0] + wss_[1] + wss_[2] + wss_[3];
        float m = S1 * (1.0f / DIMM);
        float var = S2 * (1.0f / DIMM) - m * m;
        mu_s = m;
        rs_s = rsqrtf(var + 1e-5f);
    }
    __syncthreads();
    float mu = mu_s, rs = rs_s;
    ushort_t* orow = out + (size_t)row * DIMM;
    orow[tid]       = f2b((v0 - mu) * rs * w[tid]       + b[tid]);
    orow[tid + 256] = f2b((v1 - mu) * rs * w[tid + 256] + b[tid + 256]);
    orow[tid + 512] = f2b((v2 - mu) * rs * w[tid + 512] + b[tid + 512]);
}

// ---------------------------------------------------------------- MFMA GEMM (R0 best-measured form: 64^2, reg-staged, 2 syncs)
// C[4096,N] = A[4096,768] @ W[768,N] + bias
// ASRC: 1 = bf16 row-major, 2 = bf16 gathered from [h,b,s,dh]
// OMODE: 0 = fp32 row-major, 1 = bf16 row-major, 2 = bf16 scatter to [h,b,s,dh]
// NB: fused weight count along N (bias select per 768-col group)
template<int ASRC, int OMODE, bool RELU, bool RES, int NB>
__global__ __launch_bounds__(256) void mgemm_k(const ushort_t* __restrict__ A,
                                               const ushort_t* __restrict__ BT,
                                               BPtrs bias,
                                               const float* __restrict__ res,
                                               void* __restrict__ outv)
{
    __shared__ alignas(16) ushort_t Asl[8 * 64 * 8];
    __shared__ alignas(16) ushort_t Bsl[8 * 64 * 8];
    int tid = threadIdx.x;
    int lane = tid & 63, w = tid >> 6;
    int colBase = blockIdx.x * 64, rowBase = blockIdx.y * 64;

    f32x4 acc[4];
    #pragma unroll
    for (int nt = 0; nt < 4; nt++) { f32x4 z = {0.f, 0.f, 0.f, 0.f}; acc[nt] = z; }

    int sm = tid >> 2;            // 0..63: A-row / BT-row within tile
    int sko = (tid & 3) * 16;     // k offset group

    for (int kt = 0; kt < DIMM; kt += 64) {
        // ---- stage A (bf16 16B chunks -> fragment order)
        #pragma unroll
        for (int j = 0; j < 2; j++) {
            int k = sko + j * 8;
            size_t gidx;
            if (ASRC == 1) {
                gidx = (size_t)(rowBase + sm) * DIMM + kt + k;
            } else {
                int r = rowBase + sm, kg = kt + k;
                gidx = ((size_t)((kg >> 6) * BATB + (r >> 11)) * SEQ + (r & 2047)) * DHEAD + (kg & 63);
            }
            int4 a = *(const int4*)&A[gidx];
            int ln = (sm & 15) | (((k & 31) >> 3) << 4);
            int slot = ((sm >> 4) << 1) | (k >> 5);
            *(int4*)&Asl[(slot * 64 + ln) * 8] = a;
        }
        // ---- stage B (bf16 W^T row-major -> fragment order)
        #pragma unroll
        for (int j = 0; j < 2; j++) {
            int k = sko + j * 8;
            int4 b = *(const int4*)&BT[(size_t)(colBase + sm) * DIMM + kt + k];
            int ln = (sm & 15) | (((k & 31) >> 3) << 4);
            int slot = (k >> 5) * 4 + (sm >> 4);
            *(int4*)&Bsl[(slot * 64 + ln) * 8] = b;
        }
        __syncthreads();
        bf16x8 a0 = *(bf16x8*)&Asl[((w * 2 + 0) * 64 + lane) * 8];
        bf16x8 a1 = *(bf16x8*)&Asl[((w * 2 + 1) * 64 + lane) * 8];
        #pragma unroll
        for (int nt = 0; nt < 4; nt++) {
            bf16x8 b0 = *(bf16x8*)&Bsl[((0 * 4 + nt) * 64 + lane) * 8];
            bf16x8 b1 = *(bf16x8*)&Bsl[((1 * 4 + nt) * 64 + lane) * 8];
            acc[nt] = __builtin_amdgcn_mfma_f32_16x16x32_bf16(a0, b0, acc[nt], 0, 0, 0);
            acc[nt] = __builtin_amdgcn_mfma_f32_16x16x32_bf16(a1, b1, acc[nt], 0, 0, 0);
        }
        __syncthreads();
    }
    // ---- epilogue (C layout: col = lane&15 within 16-tile, row = quad*4+reg)
    int wi = (NB == 3) ? (int)(blockIdx.x / 12) : 0;
    const float* bp_ = bias.p[wi];
    int nLoc0 = colBase - wi * DIMM;
    int col_l = lane & 15, quad = lane >> 4;
    #pragma unroll
    for (int nt = 0; nt < 4; nt++) {
        int n = colBase + nt * 16 + col_l;
        float bn = bp_[nLoc0 + nt * 16 + col_l];
        #pragma unroll
        for (int r = 0; r < 4; r++) {
            int row = rowBase + w * 16 + quad * 4 + r;
            float v = acc[nt][r] + bn;
            if (RELU) v = fmaxf(v, 0.0f);
            if (RES)  v += res[(size_t)row * DIMM + n];
            if (OMODE == 0) {
                ((float*)outv)[(size_t)row * DIMM + n] = v;
            } else if (OMODE == 1) {
                ((ushort_t*)outv)[(size_t)row * DIMM + n] = f2b(v);
            } else {
                ((ushort_t*)outv)[((size_t)((n >> 6) * BATB + (row >> 11)) * SEQ + (row & 2047)) * DHEAD + (n & 63)] = f2b(v);
            }
        }
    }
}

// ---------------------------------------------------------------- MFMA flash attention (R0 form; bias/mask issue moved AFTER barrier)
// q,k,v bf16 [hb][s][64]; bias fp32 [hb][s][s]; mask int [b][s][s]; out bf16 [hb][s][64]
// Change vs R0: the 32 bias/mask scalar loads (HBM-cold, ~900cy) are issued
// after the first __syncthreads instead of before it, so the barrier's
// implicit vmcnt(0) drain only waits on the L2-warm K/V staging loads.
// Issue -> consume window = QK^T (8 MFMA + 8 ds_read) + TLP; consumed in the
// SAME iteration, so no cross-iteration state and the closing barrier only
// drains already-consumed loads.
__global__ __launch_bounds__(256) void attn_k(const ushort_t* __restrict__ q,
                                              const ushort_t* __restrict__ k,
                                              const ushort_t* __restrict__ v,
                                              const float* __restrict__ bias,
                                              const int* __restrict__ mask,
                                              ushort_t* __restrict__ out)
{
    __shared__ alignas(16) ushort_t Kf[8 * 64 * 8];
    __shared__ alignas(16) ushort_t Vf[8 * 64 * 8];
    __shared__ alignas(16) ushort_t Pf[8 * 64 * 8];
    int tid = threadIdx.x, lane = tid & 63, w = tid >> 6;
    int col_l = lane & 15, quad = lane >> 4;
    int qbase = blockIdx.x * 64;
    int hb = blockIdx.y;
    const ushort_t* qp = q + (size_t)hb * SEQ * DHEAD;
    const ushort_t* kp = k + (size_t)hb * SEQ * DHEAD;
    const ushort_t* vp = v + (size_t)hb * SEQ * DHEAD;
    const float* bp = bias + (size_t)hb * SEQ * SEQ;
    const int*   mp = mask + (size_t)(hb & 1) * SEQ * SEQ;

    // Q A-fragments (lane holds Q[m=lane&15][(lane>>4)*8 + i]), 2 k-halves
    bf16x8 qF0 = *(const bf16x8*)&qp[(size_t)(qbase + w * 16 + col_l) * DHEAD + (quad * 8)];
    bf16x8 qF1 = *(const bf16x8*)&qp[(size_t)(qbase + w * 16 + col_l) * DHEAD + 32 + (quad * 8)];

    f32x4 O[4];
    #pragma unroll
    for (int nt = 0; nt < 4; nt++) { f32x4 z = {0.f, 0.f, 0.f, 0.f}; O[nt] = z; }
    float m_run[4], l_run[4];
    #pragma unroll
    for (int r = 0; r < 4; r++) { m_run[r] = -1e30f; l_run[r] = 0.0f; }

    int sn = tid >> 2, sko = (tid & 3) * 16;   // K staging
    int j0 = (tid >> 3) * 2, e0 = (tid & 7) * 8; // V staging (row pair)

    for (int kvb = 0; kvb < SEQ; kvb += 64) {
        // ---- stage K tile, fragment order (straight 16B copies; L2-warm)
        #pragma unroll
        for (int jj = 0; jj < 2; jj++) {
            int kk = sko + jj * 8;
            int4 kd = *(const int4*)&kp[(size_t)(kvb + sn) * DHEAD + kk];
            int slot = (kk >> 5) * 4 + (sn >> 4);
            int ln = (sn & 15) | (((kk & 31) >> 3) << 4);
            *(int4*)&Kf[(slot * 64 + ln) * 8] = kd;
        }
        // ---- stage V tile transposed into fragment order (paired rows -> b32 writes)
        {
            U16 g0, g1;
            g0.i = *(const int4*)&vp[(size_t)(kvb + j0) * DHEAD + e0];
            g1.i = *(const int4*)&vp[(size_t)(kvb + j0 + 1) * DHEAD + e0];
            int js = j0 >> 5, grp = (j0 & 31) >> 3, i0 = j0 & 7;
            #pragma unroll
            for (int c = 0; c < 8; c++) {
                int n = e0 + c;
                uint_t pk = (uint_t)g0.u[c] | ((uint_t)g1.u[c] << 16);
                int idx = ((js * 4 + (n >> 4)) * 64 + ((n & 15) | (grp << 4))) * 8 + i0;
                *(uint_t*)&Vf[idx] = pk;
            }
        }
        __syncthreads();   // drains only K/V staging (L2-warm) — bias NOT in flight here
        // ---- bias + mask loads: issued NOW, consumed after QK^T (same iteration)
        float bl[4][4]; int ml[4][4];
        #pragma unroll
        for (int nt = 0; nt < 4; nt++) {
            int col = kvb + nt * 16 + col_l;
            #pragma unroll
            for (int r = 0; r < 4; r++) {
                int qrow = qbase + w * 16 + quad * 4 + r;
                bl[nt][r] = bp[(size_t)qrow * SEQ + col];
                ml[nt][r] = mp[(size_t)qrow * SEQ + col];
            }
        }
        // ---- S = Q K^T (covers bias/mask load latency)
        f32x4 S[4];
        #pragma unroll
        for (int nt = 0; nt < 4; nt++) {
            bf16x8 b0 = *(bf16x8*)&Kf[((0 * 4 + nt) * 64 + lane) * 8];
            bf16x8 b1 = *(bf16x8*)&Kf[((1 * 4 + nt) * 64 + lane) * 8];
            f32x4 z = {0.f, 0.f, 0.f, 0.f};
            z = __builtin_amdgcn_mfma_f32_16x16x32_bf16(qF0, b0, z, 0, 0, 0);
            S[nt] = __builtin_amdgcn_mfma_f32_16x16x32_bf16(qF1, b1, z, 0, 0, 0);
        }
        // ---- logits
        float lg[4][4];
        #pragma unroll
        for (int nt = 0; nt < 4; nt++)
            #pragma unroll
            for (int r = 0; r < 4; r++)
                lg[nt][r] = ml[nt][r] ? (S[nt][r] + bl[nt][r]) * 0.125f : -1.25e19f;
        // ---- online softmax (rows live in 16-lane quads)
        float alpha[4];
        #pragma unroll
        for (int r = 0; r < 4; r++) {
            float mx = fmaxf(fmaxf(lg[0][r], lg[1][r]), fmaxf(lg[2][r], lg[3][r]));
            mx = fmaxf(mx, __shfl_xor(mx, 1));
            mx = fmaxf(mx, __shfl_xor(mx, 2));
            mx = fmaxf(mx, __shfl_xor(mx, 4));
            mx = fmaxf(mx, __shfl_xor(mx, 8));
            float mnew = fmaxf(m_run[r], mx);
            alpha[r] = __expf(m_run[r] - mnew);
            m_run[r] = mnew;
            float rs = 0.0f;
            #pragma unroll
            for (int nt = 0; nt < 4; nt++) {
                float p = __expf(lg[nt][r] - mnew);
                lg[nt][r] = p;
                rs += p;
            }
            rs += __shfl_xor(rs, 1);
            rs += __shfl_xor(rs, 2);
            rs += __shfl_xor(rs, 4);
            rs += __shfl_xor(rs, 8);
            l_run[r] = l_run[r] * alpha[r] + rs;
        }
        #pragma unroll
        for (int nt = 0; nt < 4; nt++)
            #pragma unroll
            for (int r = 0; r < 4; r++)
                O[nt][r] *= alpha[r];
        // ---- P (C-layout) -> bf16 -> Pf (A-fragment order, wave-private)
        #pragma unroll
        for (int nt = 0; nt < 4; nt++) {
            int j = nt * 16 + col_l;
            #pragma unroll
            for (int r = 0; r < 4; r++) {
                ushort_t pu = f2b(lg[nt][r]);
                uint_t po = (uint_t)(unsigned)__shfl_xor((int)pu, 1);
                if ((lane & 1) == 0) {
                    int m = quad * 4 + r;
                    int idx = ((w * 2 + (j >> 5)) * 64 + (m | (((j & 31) >> 3) << 4))) * 8 + (j & 7);
                    *(uint_t*)&Pf[idx] = (uint_t)pu | (po << 16);
                }
            }
        }
        // ---- O += P V
        #pragma unroll
        for (int js = 0; js < 2; js++) {
            bf16x8 pF = *(bf16x8*)&Pf[((w * 2 + js) * 64 + lane) * 8];
            #pragma unroll
            for (int nt = 0; nt < 4; nt++) {
                bf16x8 vF = *(bf16x8*)&Vf[((js * 4 + nt) * 64 + lane) * 8];
                O[nt] = __builtin_amdgcn_mfma_f32_16x16x32_bf16(pF, vF, O[nt], 0, 0, 0);
            }
        }
        __syncthreads();
    }
    // ---- write out bf16 [hb][s][dh]
    float inv[4];
    #pragma unroll
    for (int r = 0; r < 4; r++) inv[r] = 1.0f / l_run[r];
    #pragma unroll
    for (int nt = 0; nt < 4; nt++)
        #pragma unroll
        for (int r = 0; r < 4; r++) {
            int row = qbase + w * 16 + quad * 4 + r;
            out[((size_t)hb * SEQ + row) * DHEAD + nt * 16 + col_l] = f2b(O[nt][r] * inv[r]);
        }
}

// ---------------------------------------------------------------- launch
extern "C" void kernel_launch(void* const* d_in, const int* in_sizes, int n_in,
                              void* d_out, int out_size, void* d_ws, size_t ws_size,
                              hipStream_t stream)
{
    const float* x    = (const float*)d_in[0];
    const float* bias = (const float*)d_in[1];
    const int*   mask = (const int*)d_in[2];
    const float* ln1w = (const float*)d_in[3];
    const float* ln1b = (const float*)d_in[4];
    const float* wq   = (const float*)d_in[5];
    const float* bq   = (const float*)d_in[6];
    const float* wk   = (const float*)d_in[7];
    const float* bk   = (const float*)d_in[8];
    const float* wv   = (const float*)d_in[9];
    const float* bv   = (const float*)d_in[10];
    const float* wo   = (const float*)d_in[11];
    const float* bo   = (const float*)d_in[12];
    const float* ln2w = (const float*)d_in[13];
    const float* ln2b = (const float*)d_in[14];
    const float* w1   = (const float*)d_in[15];
    const float* b1   = (const float*)d_in[16];
    const float* w2   = (const float*)d_in[17];
    const float* b2   = (const float*)d_in[18];

    const size_t WSZ = (size_t)DIMM * DIMM;        // 589824
    const size_t ABUF = (size_t)ROWS * DIMM;       // 3145728

    ushort_t* wsu  = (ushort_t*)d_ws;
    ushort_t* wT   = wsu;                          // 6 transposed bf16 weights
    ushort_t* qb   = wsu + 6 * WSZ;
    ushort_t* kbuf = qb + ABUF;
    ushort_t* vbuf = kbuf + ABUF;
    ushort_t* xn1  = vbuf + ABUF;                  // LN1 out; reused: attnout, LN2 out
    float*    x1   = (float*)(xn1 + ABUF);         // fp32 post-attn residual
    ushort_t* hid  = qb;                           // FFN hidden reuses q

    WPtrs wp; wp.s[0] = wq; wp.s[1] = wk; wp.s[2] = wv; wp.s[3] = wo; wp.s[4] = w1; wp.s[5] = w2;
    BPtrs bqkv; bqkv.p[0] = bq; bqkv.p[1] = bk; bqkv.p[2] = bv;
    BPtrs bbo;  bbo.p[0]  = bo; bbo.p[1]  = bo; bbo.p[2]  = bo;
    BPtrs bb1;  bb1.p[0]  = b1; bb1.p[1]  = b1; bb1.p[2]  = b1;
    BPtrs bb2;  bb2.p[0]  = b2; bb2.p[1]  = b2; bb2.p[2]  = b2;

    dim3 gg(12, 64), gb(256);
    wtrans_k<<<dim3(12, 12, 6), 256, 0, stream>>>(wp, wT);
    ln_k<<<ROWS, 256, 0, stream>>>(x, ln1w, ln1b, xn1);
    // fused QKV: one GEMM, N=2304 (36 col-blocks) — also makes the GEMM visible in top-5
    mgemm_k<1, 2, false, false, 3><<<dim3(36, 64), gb, 0, stream>>>(xn1, wT, bqkv, nullptr, qb);
    attn_k<<<dim3(32, 24), 256, 0, stream>>>(qb, kbuf, vbuf, bias, mask, xn1);
    mgemm_k<2, 0, false, true, 1><<<gg, gb, 0, stream>>>(xn1, wT + 3 * WSZ, bbo, x, x1);
    ln_k<<<ROWS, 256, 0, stream>>>(x1, ln2w, ln2b, xn1);
    mgemm_k<1, 1, true, false, 1><<<gg, gb, 0, stream>>>(xn1, wT + 4 * WSZ, bb1, nullptr, hid);
    mgemm_k<1, 0, false, true, 1><<<gg, gb, 0, stream>>>(hid, wT + 5 * WSZ, bb2, x1, (float*)d_out);
}